// Round 7
// baseline (133.016 us; speedup 1.0000x reference)
//
#include <hip/hip_runtime.h>

typedef _Float16 half8 __attribute__((ext_vector_type(8)));
typedef float f32x4 __attribute__((ext_vector_type(4)));

#define MFMA16(a, b, c) __builtin_amdgcn_mfma_f32_16x16x32_f16((a), (b), (c), 0, 0, 0)

static __device__ __forceinline__ unsigned short hfbits(float f) {
  return __builtin_bit_cast(unsigned short, (_Float16)f);
}

// async global->LDS, 16B per lane; LDS dest = uniform base + lane*16
static __device__ __forceinline__ void gl16(const ushort* g, ushort* l) {
  __builtin_amdgcn_global_load_lds(
      (const __attribute__((address_space(1))) unsigned int*)g,
      (__attribute__((address_space(3))) unsigned int*)l, 16, 0, 0);
}

// ---------------------------------------------------------------------------
// Kernel 1 (merged prep): blocks [0,768): W f32 -> Wt fp16 transposed;
// blocks [768,2816): x f32 -> xh fp16 (8 elem/thread); block 768 also builds
// biasf {0,-1e9} from mask.
// ---------------------------------------------------------------------------
__global__ __launch_bounds__(256) void k_prep(const float* __restrict__ W,
                                              ushort* __restrict__ wt,
                                              const float* __restrict__ x,
                                              ushort* __restrict__ xh,
                                              const int* __restrict__ mask,
                                              float* __restrict__ biasf) {
  __shared__ ushort tile[64][72];
  const int id = blockIdx.x;
  const int t = threadIdx.x;

  if (id >= 768) {                       // ---- xh cast part
    const int pb = id - 768;
    const size_t p = ((size_t)pb * 256 + t) * 8;
    float4 a = *reinterpret_cast<const float4*>(x + p);
    float4 b = *reinterpret_cast<const float4*>(x + p + 4);
    union { ushort u[8]; uint4 v; } pk;
    pk.u[0] = hfbits(a.x); pk.u[1] = hfbits(a.y);
    pk.u[2] = hfbits(a.z); pk.u[3] = hfbits(a.w);
    pk.u[4] = hfbits(b.x); pk.u[5] = hfbits(b.y);
    pk.u[6] = hfbits(b.z); pk.u[7] = hfbits(b.w);
    *reinterpret_cast<uint4*>(xh + p) = pk.v;
    if (pb == 0) {
#pragma unroll
      for (int i = 0; i < 16; ++i) {
        int q = t + i * 256;
        biasf[q] = mask[q] ? 0.f : -1e9f;
      }
    }
    return;
  }

  // ---- Wt transpose part (id in [0,768): bx = id%48, by = id/48)
  const int n0 = (id % 48) * 64, k0 = (id / 48) * 64;
#pragma unroll
  for (int i = 0; i < 4; ++i) {
    int p = t + i * 256;
    int r = p >> 4, c = (p & 15) << 2;
    float4 v = *reinterpret_cast<const float4*>(&W[(size_t)(k0 + r) * 3072 + n0 + c]);
    ushort4 u;
    u.x = hfbits(v.x); u.y = hfbits(v.y); u.z = hfbits(v.z); u.w = hfbits(v.w);
    *reinterpret_cast<ushort4*>(&tile[r][c]) = u;
  }
  __syncthreads();
#pragma unroll
  for (int i = 0; i < 4; ++i) {
    int p = t + i * 256;
    int rn = p >> 4, ck = (p & 15) << 2;
    ushort4 u;
    u.x = tile[ck + 0][rn]; u.y = tile[ck + 1][rn];
    u.z = tile[ck + 2][rn]; u.w = tile[ck + 3][rn];
    *reinterpret_cast<ushort4*>(&wt[(size_t)(n0 + rn) * 1024 + k0 + ck]) = u;
  }
}

// ---------------------------------------------------------------------------
// Kernel 2: qkv = xh @ W (fp16, gl16-staged, XOR-swizzled LDS, m97 2-barrier
// loop, XCD-chunked decode, fused V-transpose epilogue).  Unchanged from R6.
// ---------------------------------------------------------------------------
__global__ __launch_bounds__(256) void k_gemm(const ushort* __restrict__ xh,
                                              const ushort* __restrict__ wt,
                                              ushort* __restrict__ qw,
                                              ushort* __restrict__ kw,
                                              ushort* __restrict__ vt) {
  __shared__ __align__(16) ushort sA[128 * 64];   // 16 KB linear, swizzled
  __shared__ __align__(16) ushort sB[128 * 64];   // 16 KB linear, swizzled
  const int t = threadIdx.x;
  const int lane = t & 63, w = t >> 6;
  const int g = lane >> 4, lr = lane & 15;
  const int wr = w >> 1, wc = w & 1;

  // XCD-chunked decode: chunk (xcd) = 12 bn x 8 bm, bn-fast within chunk.
  const int id = blockIdx.x;
  const int xcd = id & 7, wi = id >> 3;            // wi in 0..95
  const int bn = (xcd & 1) * 12 + wi % 12;
  const int bm = (xcd >> 1) * 8 + wi / 12;

  int srow[4], soff[4];
#pragma unroll
  for (int i = 0; i < 4; ++i) {
    const int c = 4 * w + i;
    const int r = c * 8 + (lane >> 3);
    const int sl = (lane & 7) ^ (((r & 3) << 1) ^ ((r >> 3) & 3));
    srow[i] = r;
    soff[i] = sl * 8;
  }

  int raswz[4], rbswz[4];
#pragma unroll
  for (int rs = 0; rs < 4; ++rs) {
    const int ra = wr * 64 + rs * 16 + lr;
    raswz[rs] = ((((ra & 3) << 1) ^ ((ra >> 3) & 3)) << 4);
    const int rb = wc * 64 + rs * 16 + lr;
    rbswz[rs] = ((((rb & 3) << 1) ^ ((rb >> 3) & 3)) << 4);
  }

  f32x4 acc[4][4] = {};

  for (int kt = 0; kt < 1024; kt += 64) {
#pragma unroll
    for (int i = 0; i < 4; ++i) {
      gl16(xh + (size_t)(bm * 128 + srow[i]) * 1024 + kt + soff[i],
           sA + (4 * w + i) * 512);
      gl16(wt + (size_t)(bn * 128 + srow[i]) * 1024 + kt + soff[i],
           sB + (4 * w + i) * 512);
    }
    __syncthreads();
#pragma unroll
    for (int ks = 0; ks < 64; ks += 32) {
      half8 af[4], bb[4];
#pragma unroll
      for (int rs = 0; rs < 4; ++rs) {
        const int ra = wr * 64 + rs * 16 + lr;
        af[rs] = *reinterpret_cast<const half8*>(
            (const char*)sA + ra * 128 + ((16 * g + 2 * ks) ^ raswz[rs]));
      }
#pragma unroll
      for (int cs = 0; cs < 4; ++cs) {
        const int rb = wc * 64 + cs * 16 + lr;
        bb[cs] = *reinterpret_cast<const half8*>(
            (const char*)sB + rb * 128 + ((16 * g + 2 * ks) ^ rbswz[cs]));
      }
#pragma unroll
      for (int rs = 0; rs < 4; ++rs)
#pragma unroll
        for (int cs = 0; cs < 4; ++cs)
          acc[rs][cs] = MFMA16(af[rs], bb[cs], acc[rs][cs]);
    }
    __syncthreads();
  }

  const int m0 = bm * 128 + wr * 64;
  const int n0 = bn * 128 + wc * 64;
  const int which = n0 >> 10;          // 0=q 1=k 2=v (uniform per wave)
  const int h = (n0 >> 6) & 15;

  if (which == 2) {
    ushort* q = (w < 2) ? sA + w * 4096 : sB + (w - 2) * 4096;
#pragma unroll
    for (int rs = 0; rs < 4; ++rs)
#pragma unroll
      for (int r = 0; r < 4; ++r) {
        const int m = rs * 16 + g * 4 + r;
#pragma unroll
        for (int cs = 0; cs < 4; ++cs) {
          const int n = cs * 16 + lr;
          q[n * 64 + ((((m >> 3) ^ (n & 7)) << 3) | (m & 7))] =
              hfbits(acc[rs][cs][r]);
        }
      }
    const int vb = m0 >> 11, vs = m0 & 2047;
    ushort* vbase = vt + ((size_t)((vb << 4) + h) * 64) * 2048 + vs;
#pragma unroll
    for (int j = 0; j < 8; ++j) {
      const int dl = j * 8 + (lane >> 3);
      const int mc = lane & 7;
      uint4 vv = *reinterpret_cast<const uint4*>(
          q + dl * 64 + ((mc ^ (dl & 7)) << 3));
      *reinterpret_cast<uint4*>(vbase + (size_t)dl * 2048 + mc * 8) = vv;
    }
  } else {
    ushort* dst = which == 0 ? qw : kw;
    const float qsc = which == 0 ? 1.44269504088896f : 1.0f;  // log2(e) for Q
#pragma unroll
    for (int rs = 0; rs < 4; ++rs) {
#pragma unroll
      for (int r = 0; r < 4; ++r) {
        int m = m0 + rs * 16 + g * 4 + r;
        int b = m >> 11, s = m & 2047;
        ushort* rowp = dst + ((size_t)((b << 4) + h) * 2048 + s) * 64;
#pragma unroll
        for (int cs = 0; cs < 4; ++cs)
          rowp[cs * 16 + lr] = hfbits(acc[rs][cs][r] * qsc);
      }
    }
  }
}

// ---------------------------------------------------------------------------
// Kernel 3: flash attention with T15 double-pipeline.
// PV of tile t is DEFERRED into tile t+1: there it is MFMA-independent of
// QK(t+1), so the softmax VALU chain (max tree -> exp2 -> cvt_pk) overlaps
// the PV/QK MFMA shadow instead of sitting between them on the critical
// path.  Only the packed-P (8 VGPR) is carried; V uses a 4-deep LDS
// rotation (sV[4], K stays 2-deep) so PV(prev) reads sV[(t-1)&3], which is
// not re-staged until tile t+1 (2-barrier separation -> race-free with the
// existing one-barrier-per-tile scheme).  Loop unrolled x4 for static
// buffer indices.  Tile 0 runs uniformly with P=0 against a zeroed sV[3];
// the final PV is peeled into the epilogue.  LDS 48KB, 2 blocks/CU,
// 16 waves/CU preserved.  Rescale ordering exact: PV(prev) lands in o
// before the (defer-gated) rescale; P(t) is referenced to post-rescale
// m_run and consumed next tile.
// ---------------------------------------------------------------------------
__global__ __launch_bounds__(512) void k_attn(const ushort* __restrict__ qw,
                                              const ushort* __restrict__ kw,
                                              const ushort* __restrict__ vt,
                                              const float* __restrict__ biasf,
                                              float* __restrict__ out) {
  __shared__ __align__(16) ushort sK[2][64][64];   // 16 KB (2 bufs)
  __shared__ __align__(16) ushort sV[4][64][64];   // 32 KB (4-deep rotation)

  const int t = threadIdx.x;
  const int lane = t & 63, w = t >> 6;             // w in 0..7
  const int g = lane >> 4, lr = lane & 15;

  // XCD-clustered decode: id%8 = XCD; 4 bh x 16 qblk per XCD.
  const int id = blockIdx.x;                        // 0..511
  const int j = id >> 3;
  const int bh = (id & 7) * 4 + (j >> 4);
  const int qblk = j & 15;
  const int b = bh >> 4, h = bh & 15;

  const int qrow = qblk * 128 + w * 16 + lr;
  const ushort* qp = qw + ((size_t)bh * 2048 + qrow) * 64;
  const half8 qb0 = *reinterpret_cast<const half8*>(qp + g * 8);
  const half8 qb1 = *reinterpret_cast<const half8*>(qp + 32 + g * 8);

  const ushort* kbh = kw + (size_t)bh * 2048 * 64;
  const ushort* vbh = vt + (size_t)bh * 64 * 2048;
  const float* biasb = biasf + b * 2048;

  const int krbase = (lr >> 2) * 8 + (lr & 3);
  const int kswz = (((lr & 3) << 1) ^ (lr >> 2)) << 4;

  const int sr0 = w * 8 + (lane >> 3);
  const int scb = (lane & 7) << 4;
  const int swz0 = scb ^ ((((sr0 & 3) << 1) ^ ((sr0 >> 3) & 3)) << 4);

  auto stage = [&](int kb, int vb, int jtn) {
    gl16(kbh + (size_t)(jtn + sr0) * 64 + (swz0 >> 1), &sK[kb][0][0] + w * 512);
    gl16(vbh + (size_t)sr0 * 2048 + jtn + (swz0 >> 1), &sV[vb][0][0] + w * 512);
  };

  const half8 vones = {(_Float16)1.f, (_Float16)1.f, (_Float16)1.f, (_Float16)1.f,
                       (_Float16)1.f, (_Float16)1.f, (_Float16)1.f, (_Float16)1.f};

  float m_run = -__builtin_inff();   // running max (log2 units) for q = lr
  f32x4 o[4] = {};                   // o[dn][r]: q = g*4+r, d = dn*16+lr
  f32x4 oden = {};                   // oden[r]: sum_k P[q=g*4+r][k]
  unsigned int pdP[8] = {};          // carried packed P of the previous tile

  // zero sV[3] (tile 0's "previous V"): 512 threads x 16B = 8KB
  {
    uint4 z; z.x = 0; z.y = 0; z.z = 0; z.w = 0;
    *reinterpret_cast<uint4*>(&sV[3][0][0] + (size_t)t * 8) = z;
  }
  stage(0, 0, 0);
  __syncthreads();                   // drains vmcnt(0): tile 0 landed

  // one tile: QK(cur) + PV(prev from sV[pb] x pdP) + softmax(cur)->pdP
  auto tile = [&](int jt, int kb, int vb, int pb, int nkb, int nvb) {
    const int jtn = jt + 64;
    if (jtn < 2048) stage(nkb, nvb, jtn);

    // bias rows (MFMA C-init)
    f32x4 bias4[4];
#pragma unroll
    for (int jn = 0; jn < 4; ++jn) {
      const int koff = (jn & 1) * 4 + (jn >> 1) * 32;
      bias4[jn] = *reinterpret_cast<const f32x4*>(biasb + jt + koff + g * 8);
    }

    // ---- QK(cur) from sK[kb]
    float st[4][4];
#pragma unroll
    for (int jn = 0; jn < 4; ++jn) {
      const int koff = (jn & 1) * 4 + (jn >> 1) * 32;
      const int kr = koff + krbase;
      const char* krow = (const char*)&sK[kb][kr][0];
      half8 ka0 = *reinterpret_cast<const half8*>(krow + ((16 * g) ^ kswz));
      half8 ka1 = *reinterpret_cast<const half8*>(krow + ((64 + 16 * g) ^ kswz));
      f32x4 s4 = bias4[jn];
      s4 = MFMA16(ka0, qb0, s4);
      s4 = MFMA16(ka1, qb1, s4);
#pragma unroll
      for (int r = 0; r < 4; ++r) st[jn][r] = s4[r];
    }

    // ---- PV(prev): V fragments from sV[pb], P from carried pdP
    half8 vf0[4], vf1[4];
#pragma unroll
    for (int dn = 0; dn < 4; ++dn) {
      const int vr = dn * 16 + lr;
      const int vswz = ((((lr & 3) << 1) ^ ((2 * dn + (lr >> 3)) & 3)) << 4);
      const char* vrow = (const char*)&sV[pb][vr][0];
      vf0[dn] = *reinterpret_cast<const half8*>(vrow + ((16 * g) ^ vswz));
      vf1[dn] = *reinterpret_cast<const half8*>(vrow + ((64 + 16 * g) ^ vswz));
    }
    union { unsigned int u[4]; half8 hh; } pa0u, pa1u;
    pa0u.u[0] = pdP[0]; pa0u.u[1] = pdP[1]; pa0u.u[2] = pdP[2]; pa0u.u[3] = pdP[3];
    pa1u.u[0] = pdP[4]; pa1u.u[1] = pdP[5]; pa1u.u[2] = pdP[6]; pa1u.u[3] = pdP[7];
    __builtin_amdgcn_s_setprio(1);
#pragma unroll
    for (int dn = 0; dn < 4; ++dn) {
      o[dn] = MFMA16(pa0u.hh, vf0[dn], o[dn]);
      o[dn] = MFMA16(pa1u.hh, vf1[dn], o[dn]);
    }
    oden = MFMA16(pa0u.hh, vones, oden);
    oden = MFMA16(pa1u.hh, vones, oden);
    __builtin_amdgcn_s_setprio(0);

    // ---- softmax(cur): row max (q=lr), defer-rescale, exp2, pack -> pdP
    float ma = fmaxf(fmaxf(st[0][0], st[0][1]), st[0][2]);
    ma = fmaxf(fmaxf(ma, st[0][3]), st[1][0]);
    ma = fmaxf(fmaxf(ma, st[1][1]), st[1][2]);
    ma = fmaxf(ma, st[1][3]);
    float mb2 = fmaxf(fmaxf(st[2][0], st[2][1]), st[2][2]);
    mb2 = fmaxf(fmaxf(mb2, st[2][3]), st[3][0]);
    mb2 = fmaxf(fmaxf(mb2, st[3][1]), st[3][2]);
    mb2 = fmaxf(mb2, st[3][3]);
    float tmax = fmaxf(ma, mb2);
    tmax = fmaxf(tmax, __shfl_xor(tmax, 16));
    tmax = fmaxf(tmax, __shfl_xor(tmax, 32));

    if (!__all(tmax <= m_run + 8.f)) {
      const float mnew = fmaxf(m_run, tmax);
      const float sc = __builtin_amdgcn_exp2f(m_run - mnew);  // exp2(-inf)=0
      const float s0 = __shfl(sc, g * 4 + 0);
      const float s1 = __shfl(sc, g * 4 + 1);
      const float s2 = __shfl(sc, g * 4 + 2);
      const float s3 = __shfl(sc, g * 4 + 3);
#pragma unroll
      for (int dn = 0; dn < 4; ++dn) {
        o[dn][0] *= s0; o[dn][1] *= s1; o[dn][2] *= s2; o[dn][3] *= s3;
      }
      oden[0] *= s0; oden[1] *= s1; oden[2] *= s2; oden[3] *= s3;
      m_run = mnew;
    }

#pragma unroll
    for (int jn = 0; jn < 4; ++jn) {
      float p0 = __builtin_amdgcn_exp2f(st[jn][0] - m_run);
      float p1 = __builtin_amdgcn_exp2f(st[jn][1] - m_run);
      float p2 = __builtin_amdgcn_exp2f(st[jn][2] - m_run);
      float p3 = __builtin_amdgcn_exp2f(st[jn][3] - m_run);
      pdP[jn * 2 + 0] = __builtin_bit_cast(unsigned int, __builtin_amdgcn_cvt_pkrtz(p0, p1));
      pdP[jn * 2 + 1] = __builtin_bit_cast(unsigned int, __builtin_amdgcn_cvt_pkrtz(p2, p3));
    }

    __syncthreads();   // stage landed + all reads of overwritten bufs done
  };

  // 32 tiles, unrolled x4 for static K (mod 2) / V (mod 4) buffer indices.
  for (int it = 0; it < 8; ++it) {
    const int jt = it * 256;
    tile(jt + 0,   0, 0, 3, 1, 1);
    tile(jt + 64,  1, 1, 0, 0, 2);
    tile(jt + 128, 0, 2, 1, 1, 3);
    tile(jt + 192, 1, 3, 2, 0, 0);
  }

  // ---- peeled PV of tile 31 (V in sV[3], P in pdP)
  {
    union { unsigned int u[4]; half8 hh; } pa0u, pa1u;
    pa0u.u[0] = pdP[0]; pa0u.u[1] = pdP[1]; pa0u.u[2] = pdP[2]; pa0u.u[3] = pdP[3];
    pa1u.u[0] = pdP[4]; pa1u.u[1] = pdP[5]; pa1u.u[2] = pdP[6]; pa1u.u[3] = pdP[7];
#pragma unroll
    for (int dn = 0; dn < 4; ++dn) {
      const int vr = dn * 16 + lr;
      const int vswz = ((((lr & 3) << 1) ^ ((2 * dn + (lr >> 3)) & 3)) << 4);
      const char* vrow = (const char*)&sV[3][vr][0];
      half8 vf0 = *reinterpret_cast<const half8*>(vrow + ((16 * g) ^ vswz));
      half8 vf1 = *reinterpret_cast<const half8*>(vrow + ((64 + 16 * g) ^ vswz));
      o[dn] = MFMA16(pa0u.hh, vf0, o[dn]);
      o[dn] = MFMA16(pa1u.hh, vf1, o[dn]);
    }
    oden = MFMA16(pa0u.hh, vones, oden);
    oden = MFMA16(pa1u.hh, vones, oden);
  }

  const float i0 = 1.f / oden[0];
  const float i1 = 1.f / oden[1];
  const float i2 = 1.f / oden[2];
  const float i3 = 1.f / oden[3];
  const int s0r = qblk * 128 + w * 16 + g * 4;
  float* ob = out + ((size_t)b * 2048 + s0r) * 1024 + h * 64;
#pragma unroll
  for (int dn = 0; dn < 4; ++dn) {
    ob[0 * 1024 + dn * 16 + lr] = o[dn][0] * i0;
    ob[1 * 1024 + dn * 16 + lr] = o[dn][1] * i1;
    ob[2 * 1024 + dn * 16 + lr] = o[dn][2] * i2;
    ob[3 * 1024 + dn * 16 + lr] = o[dn][3] * i3;
  }
}

// ---------------------------------------------------------------------------
extern "C" void kernel_launch(void* const* d_in, const int* in_sizes, int n_in,
                              void* d_out, int out_size, void* d_ws, size_t ws_size,
                              hipStream_t stream) {
  const float* x = (const float*)d_in[0];     // [2][2048][1024] f32
  const float* W = (const float*)d_in[1];     // [1024][3072] f32
  const int* mask = (const int*)d_in[2];      // [2][2048] i32
  float* out = (float*)d_out;                 // [2][2048][1024] f32
  char* ws = (char*)d_ws;

  ushort* wt = (ushort*)(ws);                                  // 6,291,456 B
  ushort* qw = (ushort*)(ws + 6291456);                        // 8,388,608 B
  ushort* kw = (ushort*)(ws + 6291456 + 8388608);              // 8,388,608 B
  ushort* xh = (ushort*)(ws + 6291456 + 2 * (size_t)8388608);  // 8,388,608 B
  ushort* vt = (ushort*)(ws + 6291456 + 3 * (size_t)8388608);  // 8,388,608 B
  float* biasf = (float*)(ws + 6291456 + 4 * (size_t)8388608); // 16,384 B

  k_prep<<<dim3(2816), 256, 0, stream>>>(W, wt, x, xh, mask, biasf);
  k_gemm<<<dim3(768), 256, 0, stream>>>(xh, wt, qw, kw, vt);
  k_attn<<<dim3(512), 512, 0, stream>>>(qw, kw, vt, biasf, out);
}

// Round 8
// 116.100 us; speedup vs baseline: 1.1457x; 1.1457x over previous
//
#include <hip/hip_runtime.h>

typedef _Float16 half8 __attribute__((ext_vector_type(8)));
typedef float f32x4 __attribute__((ext_vector_type(4)));

#define MFMA16(a, b, c) __builtin_amdgcn_mfma_f32_16x16x32_f16((a), (b), (c), 0, 0, 0)

static __device__ __forceinline__ unsigned short hfbits(float f) {
  return __builtin_bit_cast(unsigned short, (_Float16)f);
}

// async global->LDS, 16B per lane; LDS dest = uniform base + lane*16
static __device__ __forceinline__ void gl16(const ushort* g, ushort* l) {
  __builtin_amdgcn_global_load_lds(
      (const __attribute__((address_space(1))) unsigned int*)g,
      (__attribute__((address_space(3))) unsigned int*)l, 16, 0, 0);
}

// ---------------------------------------------------------------------------
// Kernel 1 (merged prep): blocks [0,768): W f32 -> Wt fp16 transposed;
// blocks [768,2816): x f32 -> xh fp16; block 768 also builds biasf {0,-1e9}.
// ---------------------------------------------------------------------------
__global__ __launch_bounds__(256) void k_prep(const float* __restrict__ W,
                                              ushort* __restrict__ wt,
                                              const float* __restrict__ x,
                                              ushort* __restrict__ xh,
                                              const int* __restrict__ mask,
                                              float* __restrict__ biasf) {
  __shared__ ushort tile[64][72];
  const int id = blockIdx.x;
  const int t = threadIdx.x;

  if (id >= 768) {                       // ---- xh cast part
    const int pb = id - 768;
    const size_t p = ((size_t)pb * 256 + t) * 8;
    float4 a = *reinterpret_cast<const float4*>(x + p);
    float4 b = *reinterpret_cast<const float4*>(x + p + 4);
    union { ushort u[8]; uint4 v; } pk;
    pk.u[0] = hfbits(a.x); pk.u[1] = hfbits(a.y);
    pk.u[2] = hfbits(a.z); pk.u[3] = hfbits(a.w);
    pk.u[4] = hfbits(b.x); pk.u[5] = hfbits(b.y);
    pk.u[6] = hfbits(b.z); pk.u[7] = hfbits(b.w);
    *reinterpret_cast<uint4*>(xh + p) = pk.v;
    if (pb == 0) {
#pragma unroll
      for (int i = 0; i < 16; ++i) {
        int q = t + i * 256;
        biasf[q] = mask[q] ? 0.f : -1e9f;
      }
    }
    return;
  }

  // ---- Wt transpose part
  const int n0 = (id % 48) * 64, k0 = (id / 48) * 64;
#pragma unroll
  for (int i = 0; i < 4; ++i) {
    int p = t + i * 256;
    int r = p >> 4, c = (p & 15) << 2;
    float4 v = *reinterpret_cast<const float4*>(&W[(size_t)(k0 + r) * 3072 + n0 + c]);
    ushort4 u;
    u.x = hfbits(v.x); u.y = hfbits(v.y); u.z = hfbits(v.z); u.w = hfbits(v.w);
    *reinterpret_cast<ushort4*>(&tile[r][c]) = u;
  }
  __syncthreads();
#pragma unroll
  for (int i = 0; i < 4; ++i) {
    int p = t + i * 256;
    int rn = p >> 4, ck = (p & 15) << 2;
    ushort4 u;
    u.x = tile[ck + 0][rn]; u.y = tile[ck + 1][rn];
    u.z = tile[ck + 2][rn]; u.w = tile[ck + 3][rn];
    *reinterpret_cast<ushort4*>(&wt[(size_t)(n0 + rn) * 1024 + k0 + ck]) = u;
  }
}

// ---------------------------------------------------------------------------
// Kernel 2: qkv = xh @ W (fp16, gl16-staged, XOR-swizzled LDS, 2-barrier
// loop, XCD-chunked decode, fused V-transpose epilogue).  Unchanged from R6.
// ---------------------------------------------------------------------------
__global__ __launch_bounds__(256) void k_gemm(const ushort* __restrict__ xh,
                                              const ushort* __restrict__ wt,
                                              ushort* __restrict__ qw,
                                              ushort* __restrict__ kw,
                                              ushort* __restrict__ vt) {
  __shared__ __align__(16) ushort sA[128 * 64];
  __shared__ __align__(16) ushort sB[128 * 64];
  const int t = threadIdx.x;
  const int lane = t & 63, w = t >> 6;
  const int g = lane >> 4, lr = lane & 15;
  const int wr = w >> 1, wc = w & 1;

  const int id = blockIdx.x;
  const int xcd = id & 7, wi = id >> 3;
  const int bn = (xcd & 1) * 12 + wi % 12;
  const int bm = (xcd >> 1) * 8 + wi / 12;

  int srow[4], soff[4];
#pragma unroll
  for (int i = 0; i < 4; ++i) {
    const int c = 4 * w + i;
    const int r = c * 8 + (lane >> 3);
    const int sl = (lane & 7) ^ (((r & 3) << 1) ^ ((r >> 3) & 3));
    srow[i] = r;
    soff[i] = sl * 8;
  }

  int raswz[4], rbswz[4];
#pragma unroll
  for (int rs = 0; rs < 4; ++rs) {
    const int ra = wr * 64 + rs * 16 + lr;
    raswz[rs] = ((((ra & 3) << 1) ^ ((ra >> 3) & 3)) << 4);
    const int rb = wc * 64 + rs * 16 + lr;
    rbswz[rs] = ((((rb & 3) << 1) ^ ((rb >> 3) & 3)) << 4);
  }

  f32x4 acc[4][4] = {};

  for (int kt = 0; kt < 1024; kt += 64) {
#pragma unroll
    for (int i = 0; i < 4; ++i) {
      gl16(xh + (size_t)(bm * 128 + srow[i]) * 1024 + kt + soff[i],
           sA + (4 * w + i) * 512);
      gl16(wt + (size_t)(bn * 128 + srow[i]) * 1024 + kt + soff[i],
           sB + (4 * w + i) * 512);
    }
    __syncthreads();
#pragma unroll
    for (int ks = 0; ks < 64; ks += 32) {
      half8 af[4], bb[4];
#pragma unroll
      for (int rs = 0; rs < 4; ++rs) {
        const int ra = wr * 64 + rs * 16 + lr;
        af[rs] = *reinterpret_cast<const half8*>(
            (const char*)sA + ra * 128 + ((16 * g + 2 * ks) ^ raswz[rs]));
      }
#pragma unroll
      for (int cs = 0; cs < 4; ++cs) {
        const int rb = wc * 64 + cs * 16 + lr;
        bb[cs] = *reinterpret_cast<const half8*>(
            (const char*)sB + rb * 128 + ((16 * g + 2 * ks) ^ rbswz[cs]));
      }
#pragma unroll
      for (int rs = 0; rs < 4; ++rs)
#pragma unroll
        for (int cs = 0; cs < 4; ++cs)
          acc[rs][cs] = MFMA16(af[rs], bb[cs], acc[rs][cs]);
    }
    __syncthreads();
  }

  const int m0 = bm * 128 + wr * 64;
  const int n0 = bn * 128 + wc * 64;
  const int which = n0 >> 10;
  const int h = (n0 >> 6) & 15;

  if (which == 2) {
    ushort* q = (w < 2) ? sA + w * 4096 : sB + (w - 2) * 4096;
#pragma unroll
    for (int rs = 0; rs < 4; ++rs)
#pragma unroll
      for (int r = 0; r < 4; ++r) {
        const int m = rs * 16 + g * 4 + r;
#pragma unroll
        for (int cs = 0; cs < 4; ++cs) {
          const int n = cs * 16 + lr;
          q[n * 64 + ((((m >> 3) ^ (n & 7)) << 3) | (m & 7))] =
              hfbits(acc[rs][cs][r]);
        }
      }
    const int vb = m0 >> 11, vs = m0 & 2047;
    ushort* vbase = vt + ((size_t)((vb << 4) + h) * 64) * 2048 + vs;
#pragma unroll
    for (int j = 0; j < 8; ++j) {
      const int dl = j * 8 + (lane >> 3);
      const int mc = lane & 7;
      uint4 vv = *reinterpret_cast<const uint4*>(
          q + dl * 64 + ((mc ^ (dl & 7)) << 3));
      *reinterpret_cast<uint4*>(vbase + (size_t)dl * 2048 + mc * 8) = vv;
    }
  } else {
    ushort* dst = which == 0 ? qw : kw;
    const float qsc = which == 0 ? 1.44269504088896f : 1.0f;  // log2(e) for Q
#pragma unroll
    for (int rs = 0; rs < 4; ++rs) {
#pragma unroll
      for (int r = 0; r < 4; ++r) {
        int m = m0 + rs * 16 + g * 4 + r;
        int b = m >> 11, s = m & 2047;
        ushort* rowp = dst + ((size_t)((b << 4) + h) * 2048 + s) * 64;
#pragma unroll
        for (int cs = 0; cs < 4; ++cs)
          rowp[cs * 16 + lr] = hfbits(acc[rs][cs][r] * qsc);
      }
    }
  }
}

// ---------------------------------------------------------------------------
// Kernel 3: flash attention, KV-SPLIT x2.  Inner loop is byte-identical to
// the proven R6 body (8 waves, bias-in-C, ones-column denominator MFMA,
// exp2, defer-max).  Each block covers HALF the KV range (16 tiles) ->
// grid 1024 = 4 blocks/CU = 32 waves/CU (VGPR 56 -> 8 waves/SIMD; LDS
// 4x32KB = 128KB).  Blocks emit UNNORMALIZED partials: half 0 -> out (f32),
// half 1 -> po (fp16, aliases dead xh); per-q (m, den) to pm/pden.
// k_comb merges exactly.
// ---------------------------------------------------------------------------
__global__ __launch_bounds__(512) void k_attn(const ushort* __restrict__ qw,
                                              const ushort* __restrict__ kw,
                                              const ushort* __restrict__ vt,
                                              const float* __restrict__ biasf,
                                              float* __restrict__ out,
                                              ushort* __restrict__ po,
                                              float* __restrict__ pm,
                                              float* __restrict__ pden) {
  __shared__ __align__(16) ushort sK[2][64][64];   // 16 KB (2 bufs)
  __shared__ __align__(16) ushort sV[2][64][64];   // 16 KB (2 bufs)

  const int t = threadIdx.x;
  const int lane = t & 63, w = t >> 6;             // w in 0..7
  const int g = lane >> 4, lr = lane & 15;

  // XCD-clustered decode: id%8 = XCD; 4 bh x 2 half x 16 qblk per XCD.
  const int id = blockIdx.x;                        // 0..1023
  const int j = id >> 3;                            // 0..127
  const int bh = (id & 7) * 4 + (j >> 5);
  const int half = (j >> 4) & 1;
  const int qblk = j & 15;
  const int b = bh >> 4, h = bh & 15;
  const int jt0 = half * 1024;

  const int qrow = qblk * 128 + w * 16 + lr;
  const ushort* qp = qw + ((size_t)bh * 2048 + qrow) * 64;
  const half8 qb0 = *reinterpret_cast<const half8*>(qp + g * 8);
  const half8 qb1 = *reinterpret_cast<const half8*>(qp + 32 + g * 8);

  const ushort* kbh = kw + (size_t)bh * 2048 * 64;
  const ushort* vbh = vt + (size_t)bh * 64 * 2048;
  const float* biasb = biasf + b * 2048;

  const int krbase = (lr >> 2) * 8 + (lr & 3);
  const int kswz = (((lr & 3) << 1) ^ (lr >> 2)) << 4;

  const int sr0 = w * 8 + (lane >> 3);
  const int scb = (lane & 7) << 4;
  const int swz0 = scb ^ ((((sr0 & 3) << 1) ^ ((sr0 >> 3) & 3)) << 4);

  auto stage = [&](int bufi, int jtn) {
    gl16(kbh + (size_t)(jtn + sr0) * 64 + (swz0 >> 1), &sK[bufi][0][0] + w * 512);
    gl16(vbh + (size_t)sr0 * 2048 + jtn + (swz0 >> 1), &sV[bufi][0][0] + w * 512);
  };

  const half8 vones = {(_Float16)1.f, (_Float16)1.f, (_Float16)1.f, (_Float16)1.f,
                       (_Float16)1.f, (_Float16)1.f, (_Float16)1.f, (_Float16)1.f};

  float m_run = -__builtin_inff();   // running max (log2 units) for q = lr
  f32x4 o[4] = {};                   // o[dn][r]: q = g*4+r, d = dn*16+lr
  f32x4 oden = {};                   // oden[r]: sum_k P[q=g*4+r][k]

  stage(0, jt0);
  __syncthreads();
  int buf = 0;

  for (int jt = jt0; jt < jt0 + 1024; jt += 64) {
    if (jt + 64 < jt0 + 1024) stage(buf ^ 1, jt + 64);

    f32x4 bias4[4];
#pragma unroll
    for (int jn = 0; jn < 4; ++jn) {
      const int koff = (jn & 1) * 4 + (jn >> 1) * 32;
      bias4[jn] = *reinterpret_cast<const f32x4*>(biasb + jt + koff + g * 8);
    }

    half8 vf0[4], vf1[4];
#pragma unroll
    for (int dn = 0; dn < 4; ++dn) {
      const int vr = dn * 16 + lr;
      const int vswz = ((((lr & 3) << 1) ^ ((2 * dn + (lr >> 3)) & 3)) << 4);
      const char* vrow = (const char*)&sV[buf][vr][0];
      vf0[dn] = *reinterpret_cast<const half8*>(vrow + ((16 * g) ^ vswz));
      vf1[dn] = *reinterpret_cast<const half8*>(vrow + ((64 + 16 * g) ^ vswz));
    }

    float st[4][4];
#pragma unroll
    for (int jn = 0; jn < 4; ++jn) {
      const int koff = (jn & 1) * 4 + (jn >> 1) * 32;
      const int kr = koff + krbase;
      const char* krow = (const char*)&sK[buf][kr][0];
      half8 ka0 = *reinterpret_cast<const half8*>(krow + ((16 * g) ^ kswz));
      half8 ka1 = *reinterpret_cast<const half8*>(krow + ((64 + 16 * g) ^ kswz));
      f32x4 s4 = bias4[jn];
      s4 = MFMA16(ka0, qb0, s4);
      s4 = MFMA16(ka1, qb1, s4);
#pragma unroll
      for (int r = 0; r < 4; ++r) st[jn][r] = s4[r];
    }

    float ma = fmaxf(fmaxf(st[0][0], st[0][1]), st[0][2]);
    ma = fmaxf(fmaxf(ma, st[0][3]), st[1][0]);
    ma = fmaxf(fmaxf(ma, st[1][1]), st[1][2]);
    ma = fmaxf(ma, st[1][3]);
    float mb2 = fmaxf(fmaxf(st[2][0], st[2][1]), st[2][2]);
    mb2 = fmaxf(fmaxf(mb2, st[2][3]), st[3][0]);
    mb2 = fmaxf(fmaxf(mb2, st[3][1]), st[3][2]);
    mb2 = fmaxf(mb2, st[3][3]);
    float tmax = fmaxf(ma, mb2);
    tmax = fmaxf(tmax, __shfl_xor(tmax, 16));
    tmax = fmaxf(tmax, __shfl_xor(tmax, 32));

    if (!__all(tmax <= m_run + 8.f)) {
      const float mnew = fmaxf(m_run, tmax);
      const float sc = __builtin_amdgcn_exp2f(m_run - mnew);  // exp2(-inf)=0
      const float s0 = __shfl(sc, g * 4 + 0);
      const float s1 = __shfl(sc, g * 4 + 1);
      const float s2 = __shfl(sc, g * 4 + 2);
      const float s3 = __shfl(sc, g * 4 + 3);
#pragma unroll
      for (int dn = 0; dn < 4; ++dn) {
        o[dn][0] *= s0; o[dn][1] *= s1; o[dn][2] *= s2; o[dn][3] *= s3;
      }
      oden[0] *= s0; oden[1] *= s1; oden[2] *= s2; oden[3] *= s3;
      m_run = mnew;
    }

    unsigned int pd[8];
#pragma unroll
    for (int jn = 0; jn < 4; ++jn) {
      float p0 = __builtin_amdgcn_exp2f(st[jn][0] - m_run);
      float p1 = __builtin_amdgcn_exp2f(st[jn][1] - m_run);
      float p2 = __builtin_amdgcn_exp2f(st[jn][2] - m_run);
      float p3 = __builtin_amdgcn_exp2f(st[jn][3] - m_run);
      pd[jn * 2 + 0] = __builtin_bit_cast(unsigned int, __builtin_amdgcn_cvt_pkrtz(p0, p1));
      pd[jn * 2 + 1] = __builtin_bit_cast(unsigned int, __builtin_amdgcn_cvt_pkrtz(p2, p3));
    }

    union { unsigned int u[4]; half8 h; } pa0u, pa1u;
    pa0u.u[0] = pd[0]; pa0u.u[1] = pd[1]; pa0u.u[2] = pd[2]; pa0u.u[3] = pd[3];
    pa1u.u[0] = pd[4]; pa1u.u[1] = pd[5]; pa1u.u[2] = pd[6]; pa1u.u[3] = pd[7];

    __builtin_amdgcn_s_setprio(1);
#pragma unroll
    for (int dn = 0; dn < 4; ++dn) {
      o[dn] = MFMA16(pa0u.h, vf0[dn], o[dn]);
      o[dn] = MFMA16(pa1u.h, vf1[dn], o[dn]);
    }
    oden = MFMA16(pa0u.h, vones, oden);
    oden = MFMA16(pa1u.h, vones, oden);
    __builtin_amdgcn_s_setprio(0);

    __syncthreads();
    buf ^= 1;
  }

  // ---- epilogue: UNNORMALIZED partials + (m, den) side arrays
  const int s0r = qblk * 128 + w * 16 + g * 4;
  const int qbase = bh * 2048;
  if (g == 0)                              // m for q = lr (g-replicated)
    pm[half * 65536 + qbase + qblk * 128 + w * 16 + lr] = m_run;
  if (lr == 0) {                           // den for q = g*4+r (lr-replicated)
    float* pd_h = pden + half * 65536 + qbase;
#pragma unroll
    for (int r = 0; r < 4; ++r) pd_h[s0r + r] = oden[r];
  }
  if (half == 0) {
    float* ob = out + ((size_t)b * 2048 + s0r) * 1024 + h * 64;
#pragma unroll
    for (int dn = 0; dn < 4; ++dn) {
      ob[0 * 1024 + dn * 16 + lr] = o[dn][0];
      ob[1 * 1024 + dn * 16 + lr] = o[dn][1];
      ob[2 * 1024 + dn * 16 + lr] = o[dn][2];
      ob[3 * 1024 + dn * 16 + lr] = o[dn][3];
    }
  } else {
    ushort* ob = po + ((size_t)b * 2048 + s0r) * 1024 + h * 64;
#pragma unroll
    for (int dn = 0; dn < 4; ++dn) {
      ob[0 * 1024 + dn * 16 + lr] = hfbits(o[dn][0]);
      ob[1 * 1024 + dn * 16 + lr] = hfbits(o[dn][1]);
      ob[2 * 1024 + dn * 16 + lr] = hfbits(o[dn][2]);
      ob[3 * 1024 + dn * 16 + lr] = hfbits(o[dn][3]);
    }
  }
}

// ---------------------------------------------------------------------------
// Kernel 4: merge the two KV-halves (exact online-softmax combine) and
// normalize.  out = (w1*o1 + w2*o2) / (w1*den1 + w2*den2), wi = exp2(mi-m).
// Memory-bound: ~45MB.
// ---------------------------------------------------------------------------
__global__ __launch_bounds__(256) void k_comb(float* __restrict__ out,
                                              const ushort* __restrict__ po,
                                              const float* __restrict__ pm,
                                              const float* __restrict__ pden) {
  const size_t p = ((size_t)blockIdx.x * 256 + threadIdx.x) * 8;
  const int bq = (int)(p >> 10);           // b*2048+s
  const int h = (int)((p >> 6) & 15);
  const int qi = ((bq >> 11) * 16 + h) * 2048 + (bq & 2047);
  const float m1 = pm[qi], m2 = pm[65536 + qi];
  const float mm = fmaxf(m1, m2);
  const float w1 = __builtin_amdgcn_exp2f(m1 - mm);
  const float w2 = __builtin_amdgcn_exp2f(m2 - mm);
  const float rden = 1.f / (w1 * pden[qi] + w2 * pden[65536 + qi]);
  const float c1 = w1 * rden, c2 = w2 * rden;
  float4 a = *reinterpret_cast<const float4*>(out + p);
  float4 b = *reinterpret_cast<const float4*>(out + p + 4);
  union { ushort u[8]; uint4 v; } o2;
  o2.v = *reinterpret_cast<const uint4*>(po + p);
  float4 ra, rb;
  ra.x = a.x * c1 + (float)__builtin_bit_cast(_Float16, o2.u[0]) * c2;
  ra.y = a.y * c1 + (float)__builtin_bit_cast(_Float16, o2.u[1]) * c2;
  ra.z = a.z * c1 + (float)__builtin_bit_cast(_Float16, o2.u[2]) * c2;
  ra.w = a.w * c1 + (float)__builtin_bit_cast(_Float16, o2.u[3]) * c2;
  rb.x = b.x * c1 + (float)__builtin_bit_cast(_Float16, o2.u[4]) * c2;
  rb.y = b.y * c1 + (float)__builtin_bit_cast(_Float16, o2.u[5]) * c2;
  rb.z = b.z * c1 + (float)__builtin_bit_cast(_Float16, o2.u[6]) * c2;
  rb.w = b.w * c1 + (float)__builtin_bit_cast(_Float16, o2.u[7]) * c2;
  *reinterpret_cast<float4*>(out + p) = ra;
  *reinterpret_cast<float4*>(out + p + 4) = rb;
}

// ---------------------------------------------------------------------------
extern "C" void kernel_launch(void* const* d_in, const int* in_sizes, int n_in,
                              void* d_out, int out_size, void* d_ws, size_t ws_size,
                              hipStream_t stream) {
  const float* x = (const float*)d_in[0];     // [2][2048][1024] f32
  const float* W = (const float*)d_in[1];     // [1024][3072] f32
  const int* mask = (const int*)d_in[2];      // [2][2048] i32
  float* out = (float*)d_out;                 // [2][2048][1024] f32
  char* ws = (char*)d_ws;

  ushort* wt = (ushort*)(ws);                                  // 6,291,456 B
  ushort* qw = (ushort*)(ws + 6291456);                        // 8,388,608 B
  ushort* kw = (ushort*)(ws + 6291456 + 8388608);              // 8,388,608 B
  ushort* xh = (ushort*)(ws + 6291456 + 2 * (size_t)8388608);  // 8,388,608 B
  ushort* vt = (ushort*)(ws + 6291456 + 3 * (size_t)8388608);  // 8,388,608 B
  float* biasf = (float*)(ws + 6291456 + 4 * (size_t)8388608); // 16,384 B
  float* pm    = (float*)(ws + 6291456 + 4 * (size_t)8388608 + 16384);            // 524,288 B
  float* pden  = (float*)(ws + 6291456 + 4 * (size_t)8388608 + 16384 + 524288);   // 524,288 B
  // po (fp16 half-1 partial O) ALIASES xh: xh is dead after k_gemm.
  ushort* po = xh;

  k_prep<<<dim3(2816), 256, 0, stream>>>(W, wt, x, xh, mask, biasf);
  k_gemm<<<dim3(768), 256, 0, stream>>>(xh, wt, qw, kw, vt);
  k_attn<<<dim3(1024), 512, 0, stream>>>(qw, kw, vt, biasf, out, po, pm, pden);
  k_comb<<<dim3(2048), 256, 0, stream>>>(out, po, pm, pden);
}

// Round 9
// 109.400 us; speedup vs baseline: 1.2159x; 1.0612x over previous
//
#include <hip/hip_runtime.h>

typedef _Float16 half8 __attribute__((ext_vector_type(8)));
typedef float f32x4 __attribute__((ext_vector_type(4)));

#define MFMA16(a, b, c) __builtin_amdgcn_mfma_f32_16x16x32_f16((a), (b), (c), 0, 0, 0)

static __device__ __forceinline__ unsigned short hfbits(float f) {
  return __builtin_bit_cast(unsigned short, (_Float16)f);
}

// async global->LDS, 16B per lane; LDS dest = uniform base + lane*16
static __device__ __forceinline__ void gl16(const ushort* g, ushort* l) {
  __builtin_amdgcn_global_load_lds(
      (const __attribute__((address_space(1))) unsigned int*)g,
      (__attribute__((address_space(3))) unsigned int*)l, 16, 0, 0);
}

// ---------------------------------------------------------------------------
// Kernel 1 (merged prep): blocks [0,768): W f32 -> Wt fp16 transposed;
// blocks [768,2816): x f32 -> xh fp16; block 768 also builds biasf {0,-1e9}.
// ---------------------------------------------------------------------------
__global__ __launch_bounds__(256) void k_prep(const float* __restrict__ W,
                                              ushort* __restrict__ wt,
                                              const float* __restrict__ x,
                                              ushort* __restrict__ xh,
                                              const int* __restrict__ mask,
                                              float* __restrict__ biasf) {
  __shared__ ushort tile[64][72];
  const int id = blockIdx.x;
  const int t = threadIdx.x;

  if (id >= 768) {                       // ---- xh cast part
    const int pb = id - 768;
    const size_t p = ((size_t)pb * 256 + t) * 8;
    float4 a = *reinterpret_cast<const float4*>(x + p);
    float4 b = *reinterpret_cast<const float4*>(x + p + 4);
    union { ushort u[8]; uint4 v; } pk;
    pk.u[0] = hfbits(a.x); pk.u[1] = hfbits(a.y);
    pk.u[2] = hfbits(a.z); pk.u[3] = hfbits(a.w);
    pk.u[4] = hfbits(b.x); pk.u[5] = hfbits(b.y);
    pk.u[6] = hfbits(b.z); pk.u[7] = hfbits(b.w);
    *reinterpret_cast<uint4*>(xh + p) = pk.v;
    if (pb == 0) {
#pragma unroll
      for (int i = 0; i < 16; ++i) {
        int q = t + i * 256;
        biasf[q] = mask[q] ? 0.f : -1e9f;
      }
    }
    return;
  }

  // ---- Wt transpose part
  const int n0 = (id % 48) * 64, k0 = (id / 48) * 64;
#pragma unroll
  for (int i = 0; i < 4; ++i) {
    int p = t + i * 256;
    int r = p >> 4, c = (p & 15) << 2;
    float4 v = *reinterpret_cast<const float4*>(&W[(size_t)(k0 + r) * 3072 + n0 + c]);
    ushort4 u;
    u.x = hfbits(v.x); u.y = hfbits(v.y); u.z = hfbits(v.z); u.w = hfbits(v.w);
    *reinterpret_cast<ushort4*>(&tile[r][c]) = u;
  }
  __syncthreads();
#pragma unroll
  for (int i = 0; i < 4; ++i) {
    int p = t + i * 256;
    int rn = p >> 4, ck = (p & 15) << 2;
    ushort4 u;
    u.x = tile[ck + 0][rn]; u.y = tile[ck + 1][rn];
    u.z = tile[ck + 2][rn]; u.w = tile[ck + 3][rn];
    *reinterpret_cast<ushort4*>(&wt[(size_t)(n0 + rn) * 1024 + k0 + ck]) = u;
  }
}

// ---------------------------------------------------------------------------
// Kernel 2: qkv = xh @ W (fp16, gl16-staged, XOR-swizzled LDS, 2-barrier
// loop, XCD-chunked decode, fused V-transpose epilogue).  Unchanged from R6.
// ---------------------------------------------------------------------------
__global__ __launch_bounds__(256) void k_gemm(const ushort* __restrict__ xh,
                                              const ushort* __restrict__ wt,
                                              ushort* __restrict__ qw,
                                              ushort* __restrict__ kw,
                                              ushort* __restrict__ vt) {
  __shared__ __align__(16) ushort sA[128 * 64];
  __shared__ __align__(16) ushort sB[128 * 64];
  const int t = threadIdx.x;
  const int lane = t & 63, w = t >> 6;
  const int g = lane >> 4, lr = lane & 15;
  const int wr = w >> 1, wc = w & 1;

  const int id = blockIdx.x;
  const int xcd = id & 7, wi = id >> 3;
  const int bn = (xcd & 1) * 12 + wi % 12;
  const int bm = (xcd >> 1) * 8 + wi / 12;

  int srow[4], soff[4];
#pragma unroll
  for (int i = 0; i < 4; ++i) {
    const int c = 4 * w + i;
    const int r = c * 8 + (lane >> 3);
    const int sl = (lane & 7) ^ (((r & 3) << 1) ^ ((r >> 3) & 3));
    srow[i] = r;
    soff[i] = sl * 8;
  }

  int raswz[4], rbswz[4];
#pragma unroll
  for (int rs = 0; rs < 4; ++rs) {
    const int ra = wr * 64 + rs * 16 + lr;
    raswz[rs] = ((((ra & 3) << 1) ^ ((ra >> 3) & 3)) << 4);
    const int rb = wc * 64 + rs * 16 + lr;
    rbswz[rs] = ((((rb & 3) << 1) ^ ((rb >> 3) & 3)) << 4);
  }

  f32x4 acc[4][4] = {};

  for (int kt = 0; kt < 1024; kt += 64) {
#pragma unroll
    for (int i = 0; i < 4; ++i) {
      gl16(xh + (size_t)(bm * 128 + srow[i]) * 1024 + kt + soff[i],
           sA + (4 * w + i) * 512);
      gl16(wt + (size_t)(bn * 128 + srow[i]) * 1024 + kt + soff[i],
           sB + (4 * w + i) * 512);
    }
    __syncthreads();
#pragma unroll
    for (int ks = 0; ks < 64; ks += 32) {
      half8 af[4], bb[4];
#pragma unroll
      for (int rs = 0; rs < 4; ++rs) {
        const int ra = wr * 64 + rs * 16 + lr;
        af[rs] = *reinterpret_cast<const half8*>(
            (const char*)sA + ra * 128 + ((16 * g + 2 * ks) ^ raswz[rs]));
      }
#pragma unroll
      for (int cs = 0; cs < 4; ++cs) {
        const int rb = wc * 64 + cs * 16 + lr;
        bb[cs] = *reinterpret_cast<const half8*>(
            (const char*)sB + rb * 128 + ((16 * g + 2 * ks) ^ rbswz[cs]));
      }
#pragma unroll
      for (int rs = 0; rs < 4; ++rs)
#pragma unroll
        for (int cs = 0; cs < 4; ++cs)
          acc[rs][cs] = MFMA16(af[rs], bb[cs], acc[rs][cs]);
    }
    __syncthreads();
  }

  const int m0 = bm * 128 + wr * 64;
  const int n0 = bn * 128 + wc * 64;
  const int which = n0 >> 10;
  const int h = (n0 >> 6) & 15;

  if (which == 2) {
    ushort* q = (w < 2) ? sA + w * 4096 : sB + (w - 2) * 4096;
#pragma unroll
    for (int rs = 0; rs < 4; ++rs)
#pragma unroll
      for (int r = 0; r < 4; ++r) {
        const int m = rs * 16 + g * 4 + r;
#pragma unroll
        for (int cs = 0; cs < 4; ++cs) {
          const int n = cs * 16 + lr;
          q[n * 64 + ((((m >> 3) ^ (n & 7)) << 3) | (m & 7))] =
              hfbits(acc[rs][cs][r]);
        }
      }
    const int vb = m0 >> 11, vs = m0 & 2047;
    ushort* vbase = vt + ((size_t)((vb << 4) + h) * 64) * 2048 + vs;
#pragma unroll
    for (int j = 0; j < 8; ++j) {
      const int dl = j * 8 + (lane >> 3);
      const int mc = lane & 7;
      uint4 vv = *reinterpret_cast<const uint4*>(
          q + dl * 64 + ((mc ^ (dl & 7)) << 3));
      *reinterpret_cast<uint4*>(vbase + (size_t)dl * 2048 + mc * 8) = vv;
    }
  } else {
    ushort* dst = which == 0 ? qw : kw;
    const float qsc = which == 0 ? 1.44269504088896f : 1.0f;  // log2(e) for Q
#pragma unroll
    for (int rs = 0; rs < 4; ++rs) {
#pragma unroll
      for (int r = 0; r < 4; ++r) {
        int m = m0 + rs * 16 + g * 4 + r;
        int b = m >> 11, s = m & 2047;
        ushort* rowp = dst + ((size_t)((b << 4) + h) * 2048 + s) * 64;
#pragma unroll
        for (int cs = 0; cs < 4; ++cs)
          rowp[cs * 16 + lr] = hfbits(acc[rs][cs][r] * qsc);
      }
    }
  }
}

// ---------------------------------------------------------------------------
// Kernel 3: flash attention, 32 q-rows per wave (two 16-row groups A/B
// SHARING every K/V fragment read) + KV-split x2.
// R8 diagnosis: per-CU LDS pipe saturated (8192 b128 x 12cyc + conflicts
// ~= 55us ~= measured 62.5); all waves read identical K/V fragments, so
// doubling q per wave halves LDS bytes per unit work.  R3's version of this
// failed because it also halved occupancy; here blocks stay 512-thr/8-wave
// (grid 512 via KV-split = 2 blocks/CU = 16 waves/CU) and the R4 VALU diet
// is retained.  __launch_bounds__(512,4) pins VGPR <= 128 so both blocks
// stay resident.  Partials merged exactly by k_comb (proven in R8).
// ---------------------------------------------------------------------------
__global__ __launch_bounds__(512, 4) void k_attn(const ushort* __restrict__ qw,
                                                 const ushort* __restrict__ kw,
                                                 const ushort* __restrict__ vt,
                                                 const float* __restrict__ biasf,
                                                 float* __restrict__ out,
                                                 ushort* __restrict__ po,
                                                 float* __restrict__ pm,
                                                 float* __restrict__ pden) {
  __shared__ __align__(16) ushort sK[2][64][64];   // 16 KB (2 bufs)
  __shared__ __align__(16) ushort sV[2][64][64];   // 16 KB (2 bufs)

  const int t = threadIdx.x;
  const int lane = t & 63, w = t >> 6;             // w in 0..7
  const int g = lane >> 4, lr = lane & 15;

  // XCD-clustered decode: id%8 = XCD; 4 bh x 2 half x 8 qblk per XCD.
  const int id = blockIdx.x;                        // 0..511
  const int j = id >> 3;                            // 0..63
  const int bh = (id & 7) * 4 + (j >> 4);
  const int half = (j >> 3) & 1;
  const int qblk = j & 7;
  const int b = bh >> 4, h = bh & 15;
  const int jt0 = half * 1024;

  // Q for both 16-row groups (B-operand; B col = lane&15 = q-row in group)
  const int qrowA = qblk * 256 + w * 32 + lr;
  const ushort* qpA = qw + ((size_t)bh * 2048 + qrowA) * 64;
  const half8 qA0 = *reinterpret_cast<const half8*>(qpA + g * 8);
  const half8 qA1 = *reinterpret_cast<const half8*>(qpA + 32 + g * 8);
  const ushort* qpB = qpA + 16 * 64;
  const half8 qB0 = *reinterpret_cast<const half8*>(qpB + g * 8);
  const half8 qB1 = *reinterpret_cast<const half8*>(qpB + 32 + g * 8);

  const ushort* kbh = kw + (size_t)bh * 2048 * 64;
  const ushort* vbh = vt + (size_t)bh * 64 * 2048;
  const float* biasb = biasf + b * 2048;

  const int krbase = (lr >> 2) * 8 + (lr & 3);
  const int kswz = (((lr & 3) << 1) ^ (lr >> 2)) << 4;

  const int sr0 = w * 8 + (lane >> 3);
  const int scb = (lane & 7) << 4;
  const int swz0 = scb ^ ((((sr0 & 3) << 1) ^ ((sr0 >> 3) & 3)) << 4);

  auto stage = [&](int bufi, int jtn) {
    gl16(kbh + (size_t)(jtn + sr0) * 64 + (swz0 >> 1), &sK[bufi][0][0] + w * 512);
    gl16(vbh + (size_t)sr0 * 2048 + jtn + (swz0 >> 1), &sV[bufi][0][0] + w * 512);
  };

  const half8 vones = {(_Float16)1.f, (_Float16)1.f, (_Float16)1.f, (_Float16)1.f,
                       (_Float16)1.f, (_Float16)1.f, (_Float16)1.f, (_Float16)1.f};

  float mA = -__builtin_inff(), mB = -__builtin_inff();
  f32x4 oA[4] = {}, oB[4] = {};
  f32x4 odenA = {}, odenB = {};

  // softmax for one group: st -> (m_run, o-rescale, oden-rescale, packed pd)
  auto sm_step = [&](float (&st)[4][4], float& m_run, f32x4 (&o)[4],
                     f32x4& oden, unsigned int (&pd)[8]) {
    float ma = fmaxf(fmaxf(st[0][0], st[0][1]), st[0][2]);
    ma = fmaxf(fmaxf(ma, st[0][3]), st[1][0]);
    ma = fmaxf(fmaxf(ma, st[1][1]), st[1][2]);
    ma = fmaxf(ma, st[1][3]);
    float mb2 = fmaxf(fmaxf(st[2][0], st[2][1]), st[2][2]);
    mb2 = fmaxf(fmaxf(mb2, st[2][3]), st[3][0]);
    mb2 = fmaxf(fmaxf(mb2, st[3][1]), st[3][2]);
    mb2 = fmaxf(mb2, st[3][3]);
    float tmax = fmaxf(ma, mb2);
    tmax = fmaxf(tmax, __shfl_xor(tmax, 16));
    tmax = fmaxf(tmax, __shfl_xor(tmax, 32));

    if (!__all(tmax <= m_run + 8.f)) {
      const float mnew = fmaxf(m_run, tmax);
      const float sc = __builtin_amdgcn_exp2f(m_run - mnew);  // exp2(-inf)=0
      const float s0 = __shfl(sc, g * 4 + 0);
      const float s1 = __shfl(sc, g * 4 + 1);
      const float s2 = __shfl(sc, g * 4 + 2);
      const float s3 = __shfl(sc, g * 4 + 3);
#pragma unroll
      for (int dn = 0; dn < 4; ++dn) {
        o[dn][0] *= s0; o[dn][1] *= s1; o[dn][2] *= s2; o[dn][3] *= s3;
      }
      oden[0] *= s0; oden[1] *= s1; oden[2] *= s2; oden[3] *= s3;
      m_run = mnew;
    }

#pragma unroll
    for (int jn = 0; jn < 4; ++jn) {
      float p0 = __builtin_amdgcn_exp2f(st[jn][0] - m_run);
      float p1 = __builtin_amdgcn_exp2f(st[jn][1] - m_run);
      float p2 = __builtin_amdgcn_exp2f(st[jn][2] - m_run);
      float p3 = __builtin_amdgcn_exp2f(st[jn][3] - m_run);
      pd[jn * 2 + 0] = __builtin_bit_cast(unsigned int, __builtin_amdgcn_cvt_pkrtz(p0, p1));
      pd[jn * 2 + 1] = __builtin_bit_cast(unsigned int, __builtin_amdgcn_cvt_pkrtz(p2, p3));
    }
  };

  stage(0, jt0);
  __syncthreads();
  int buf = 0;

  for (int jt = jt0; jt < jt0 + 1024; jt += 64) {
    if (jt + 64 < jt0 + 1024) stage(buf ^ 1, jt + 64);

    // ---- QK for BOTH groups (K fragments read once)
    float stA[4][4], stB[4][4];
#pragma unroll
    for (int jn = 0; jn < 4; ++jn) {
      const int koff = (jn & 1) * 4 + (jn >> 1) * 32;
      const f32x4 bias4 = *reinterpret_cast<const f32x4*>(biasb + jt + koff + g * 8);
      const int kr = koff + krbase;
      const char* krow = (const char*)&sK[buf][kr][0];
      half8 ka0 = *reinterpret_cast<const half8*>(krow + ((16 * g) ^ kswz));
      half8 ka1 = *reinterpret_cast<const half8*>(krow + ((64 + 16 * g) ^ kswz));
      f32x4 s4A = bias4;
      s4A = MFMA16(ka0, qA0, s4A);
      s4A = MFMA16(ka1, qA1, s4A);
      f32x4 s4B = bias4;
      s4B = MFMA16(ka0, qB0, s4B);
      s4B = MFMA16(ka1, qB1, s4B);
#pragma unroll
      for (int r = 0; r < 4; ++r) { stA[jn][r] = s4A[r]; stB[jn][r] = s4B[r]; }
    }

    // ---- softmax both groups (VALU; overlaps other waves' MFMA)
    unsigned int pdA[8], pdB[8];
    sm_step(stA, mA, oA, odenA, pdA);
    sm_step(stB, mB, oB, odenB, pdB);

    // ---- V fragments read once, PV for both groups
    half8 vf0[4], vf1[4];
#pragma unroll
    for (int dn = 0; dn < 4; ++dn) {
      const int vr = dn * 16 + lr;
      const int vswz = ((((lr & 3) << 1) ^ ((2 * dn + (lr >> 3)) & 3)) << 4);
      const char* vrow = (const char*)&sV[buf][vr][0];
      vf0[dn] = *reinterpret_cast<const half8*>(vrow + ((16 * g) ^ vswz));
      vf1[dn] = *reinterpret_cast<const half8*>(vrow + ((64 + 16 * g) ^ vswz));
    }
    union { unsigned int u[4]; half8 hh; } a0, a1, b0, b1;
    a0.u[0] = pdA[0]; a0.u[1] = pdA[1]; a0.u[2] = pdA[2]; a0.u[3] = pdA[3];
    a1.u[0] = pdA[4]; a1.u[1] = pdA[5]; a1.u[2] = pdA[6]; a1.u[3] = pdA[7];
    b0.u[0] = pdB[0]; b0.u[1] = pdB[1]; b0.u[2] = pdB[2]; b0.u[3] = pdB[3];
    b1.u[0] = pdB[4]; b1.u[1] = pdB[5]; b1.u[2] = pdB[6]; b1.u[3] = pdB[7];

    __builtin_amdgcn_s_setprio(1);
#pragma unroll
    for (int dn = 0; dn < 4; ++dn) {
      oA[dn] = MFMA16(a0.hh, vf0[dn], oA[dn]);
      oA[dn] = MFMA16(a1.hh, vf1[dn], oA[dn]);
      oB[dn] = MFMA16(b0.hh, vf0[dn], oB[dn]);
      oB[dn] = MFMA16(b1.hh, vf1[dn], oB[dn]);
    }
    odenA = MFMA16(a0.hh, vones, odenA);
    odenA = MFMA16(a1.hh, vones, odenA);
    odenB = MFMA16(b0.hh, vones, odenB);
    odenB = MFMA16(b1.hh, vones, odenB);
    __builtin_amdgcn_s_setprio(0);

    __syncthreads();
    buf ^= 1;
  }

  // ---- epilogue: UNNORMALIZED partials + (m, den) side arrays, both groups
  const int qbase = bh * 2048;
  const int qA = qblk * 256 + w * 32;          // wave's group-A base row
  if (g == 0) {
    pm[half * 65536 + qbase + qA + lr] = mA;
    pm[half * 65536 + qbase + qA + 16 + lr] = mB;
  }
  if (lr == 0) {
    float* pd_h = pden + half * 65536 + qbase;
#pragma unroll
    for (int r = 0; r < 4; ++r) {
      pd_h[qA + g * 4 + r] = odenA[r];
      pd_h[qA + 16 + g * 4 + r] = odenB[r];
    }
  }
  auto wout = [&](f32x4 (&o)[4], int s0r) {
    if (half == 0) {
      float* ob = out + ((size_t)b * 2048 + s0r) * 1024 + h * 64;
#pragma unroll
      for (int dn = 0; dn < 4; ++dn) {
        ob[0 * 1024 + dn * 16 + lr] = o[dn][0];
        ob[1 * 1024 + dn * 16 + lr] = o[dn][1];
        ob[2 * 1024 + dn * 16 + lr] = o[dn][2];
        ob[3 * 1024 + dn * 16 + lr] = o[dn][3];
      }
    } else {
      ushort* ob = po + ((size_t)b * 2048 + s0r) * 1024 + h * 64;
#pragma unroll
      for (int dn = 0; dn < 4; ++dn) {
        ob[0 * 1024 + dn * 16 + lr] = hfbits(o[dn][0]);
        ob[1 * 1024 + dn * 16 + lr] = hfbits(o[dn][1]);
        ob[2 * 1024 + dn * 16 + lr] = hfbits(o[dn][2]);
        ob[3 * 1024 + dn * 16 + lr] = hfbits(o[dn][3]);
      }
    }
  };
  wout(oA, qA + g * 4);
  wout(oB, qA + 16 + g * 4);
}

// ---------------------------------------------------------------------------
// Kernel 4: merge the two KV-halves (exact online-softmax combine) and
// normalize.  out = (w1*o1 + w2*o2) / (w1*den1 + w2*den2), wi = exp2(mi-m).
// ---------------------------------------------------------------------------
__global__ __launch_bounds__(256) void k_comb(float* __restrict__ out,
                                              const ushort* __restrict__ po,
                                              const float* __restrict__ pm,
                                              const float* __restrict__ pden) {
  const size_t p = ((size_t)blockIdx.x * 256 + threadIdx.x) * 8;
  const int bq = (int)(p >> 10);           // b*2048+s
  const int h = (int)((p >> 6) & 15);
  const int qi = ((bq >> 11) * 16 + h) * 2048 + (bq & 2047);
  const float m1 = pm[qi], m2 = pm[65536 + qi];
  const float mm = fmaxf(m1, m2);
  const float w1 = __builtin_amdgcn_exp2f(m1 - mm);
  const float w2 = __builtin_amdgcn_exp2f(m2 - mm);
  const float rden = 1.f / (w1 * pden[qi] + w2 * pden[65536 + qi]);
  const float c1 = w1 * rden, c2 = w2 * rden;
  float4 a = *reinterpret_cast<const float4*>(out + p);
  float4 b = *reinterpret_cast<const float4*>(out + p + 4);
  union { ushort u[8]; uint4 v; } o2;
  o2.v = *reinterpret_cast<const uint4*>(po + p);
  float4 ra, rb;
  ra.x = a.x * c1 + (float)__builtin_bit_cast(_Float16, o2.u[0]) * c2;
  ra.y = a.y * c1 + (float)__builtin_bit_cast(_Float16, o2.u[1]) * c2;
  ra.z = a.z * c1 + (float)__builtin_bit_cast(_Float16, o2.u[2]) * c2;
  ra.w = a.w * c1 + (float)__builtin_bit_cast(_Float16, o2.u[3]) * c2;
  rb.x = b.x * c1 + (float)__builtin_bit_cast(_Float16, o2.u[4]) * c2;
  rb.y = b.y * c1 + (float)__builtin_bit_cast(_Float16, o2.u[5]) * c2;
  rb.z = b.z * c1 + (float)__builtin_bit_cast(_Float16, o2.u[6]) * c2;
  rb.w = b.w * c1 + (float)__builtin_bit_cast(_Float16, o2.u[7]) * c2;
  *reinterpret_cast<float4*>(out + p) = ra;
  *reinterpret_cast<float4*>(out + p + 4) = rb;
}

// ---------------------------------------------------------------------------
extern "C" void kernel_launch(void* const* d_in, const int* in_sizes, int n_in,
                              void* d_out, int out_size, void* d_ws, size_t ws_size,
                              hipStream_t stream) {
  const float* x = (const float*)d_in[0];     // [2][2048][1024] f32
  const float* W = (const float*)d_in[1];     // [1024][3072] f32
  const int* mask = (const int*)d_in[2];      // [2][2048] i32
  float* out = (float*)d_out;                 // [2][2048][1024] f32
  char* ws = (char*)d_ws;

  ushort* wt = (ushort*)(ws);                                  // 6,291,456 B
  ushort* qw = (ushort*)(ws + 6291456);                        // 8,388,608 B
  ushort* kw = (ushort*)(ws + 6291456 + 8388608);              // 8,388,608 B
  ushort* xh = (ushort*)(ws + 6291456 + 2 * (size_t)8388608);  // 8,388,608 B
  ushort* vt = (ushort*)(ws + 6291456 + 3 * (size_t)8388608);  // 8,388,608 B
  float* biasf = (float*)(ws + 6291456 + 4 * (size_t)8388608); // 16,384 B
  float* pm    = (float*)(ws + 6291456 + 4 * (size_t)8388608 + 16384);            // 524,288 B
  float* pden  = (float*)(ws + 6291456 + 4 * (size_t)8388608 + 16384 + 524288);   // 524,288 B
  // po (fp16 half-1 partial O) ALIASES xh: xh is dead after k_gemm.
  ushort* po = xh;

  k_prep<<<dim3(2816), 256, 0, stream>>>(W, wt, x, xh, mask, biasf);
  k_gemm<<<dim3(768), 256, 0, stream>>>(xh, wt, qw, kw, vt);
  k_attn<<<dim3(512), 512, 0, stream>>>(qw, kw, vt, biasf, out, po, pm, pden);
  k_comb<<<dim3(2048), 256, 0, stream>>>(out, po, pm, pden);
}

// Round 10
// 104.477 us; speedup vs baseline: 1.2732x; 1.0471x over previous
//
#include <hip/hip_runtime.h>

typedef _Float16 half8 __attribute__((ext_vector_type(8)));
typedef float f32x4 __attribute__((ext_vector_type(4)));

#define MFMA16(a, b, c) __builtin_amdgcn_mfma_f32_16x16x32_f16((a), (b), (c), 0, 0, 0)

static __device__ __forceinline__ unsigned short hfbits(float f) {
  return __builtin_bit_cast(unsigned short, (_Float16)f);
}

// async global->LDS, 16B per lane; LDS dest = uniform base + lane*16
static __device__ __forceinline__ void gl16(const ushort* g, ushort* l) {
  __builtin_amdgcn_global_load_lds(
      (const __attribute__((address_space(1))) unsigned int*)g,
      (__attribute__((address_space(3))) unsigned int*)l, 16, 0, 0);
}

// ---------------------------------------------------------------------------
// Kernel 1 (merged prep): blocks [0,768): W f32 -> Wt fp16 transposed;
// blocks [768,2816): x f32 -> xh fp16; block 768 also builds biasf {0,-1e9}.
// ---------------------------------------------------------------------------
__global__ __launch_bounds__(256) void k_prep(const float* __restrict__ W,
                                              ushort* __restrict__ wt,
                                              const float* __restrict__ x,
                                              ushort* __restrict__ xh,
                                              const int* __restrict__ mask,
                                              float* __restrict__ biasf) {
  __shared__ ushort tile[64][72];
  const int id = blockIdx.x;
  const int t = threadIdx.x;

  if (id >= 768) {                       // ---- xh cast part
    const int pb = id - 768;
    const size_t p = ((size_t)pb * 256 + t) * 8;
    float4 a = *reinterpret_cast<const float4*>(x + p);
    float4 b = *reinterpret_cast<const float4*>(x + p + 4);
    union { ushort u[8]; uint4 v; } pk;
    pk.u[0] = hfbits(a.x); pk.u[1] = hfbits(a.y);
    pk.u[2] = hfbits(a.z); pk.u[3] = hfbits(a.w);
    pk.u[4] = hfbits(b.x); pk.u[5] = hfbits(b.y);
    pk.u[6] = hfbits(b.z); pk.u[7] = hfbits(b.w);
    *reinterpret_cast<uint4*>(xh + p) = pk.v;
    if (pb == 0) {
#pragma unroll
      for (int i = 0; i < 16; ++i) {
        int q = t + i * 256;
        biasf[q] = mask[q] ? 0.f : -1e9f;
      }
    }
    return;
  }

  // ---- Wt transpose part
  const int n0 = (id % 48) * 64, k0 = (id / 48) * 64;
#pragma unroll
  for (int i = 0; i < 4; ++i) {
    int p = t + i * 256;
    int r = p >> 4, c = (p & 15) << 2;
    float4 v = *reinterpret_cast<const float4*>(&W[(size_t)(k0 + r) * 3072 + n0 + c]);
    ushort4 u;
    u.x = hfbits(v.x); u.y = hfbits(v.y); u.z = hfbits(v.z); u.w = hfbits(v.w);
    *reinterpret_cast<ushort4*>(&tile[r][c]) = u;
  }
  __syncthreads();
#pragma unroll
  for (int i = 0; i < 4; ++i) {
    int p = t + i * 256;
    int rn = p >> 4, ck = (p & 15) << 2;
    ushort4 u;
    u.x = tile[ck + 0][rn]; u.y = tile[ck + 1][rn];
    u.z = tile[ck + 2][rn]; u.w = tile[ck + 3][rn];
    *reinterpret_cast<ushort4*>(&wt[(size_t)(n0 + rn) * 1024 + k0 + ck]) = u;
  }
}

// ---------------------------------------------------------------------------
// Kernel 2: qkv = xh @ W (fp16, gl16-staged, XOR-swizzled LDS, 2-barrier
// loop, XCD-chunked decode, fused V-transpose epilogue).  Unchanged from R6.
// ---------------------------------------------------------------------------
__global__ __launch_bounds__(256) void k_gemm(const ushort* __restrict__ xh,
                                              const ushort* __restrict__ wt,
                                              ushort* __restrict__ qw,
                                              ushort* __restrict__ kw,
                                              ushort* __restrict__ vt) {
  __shared__ __align__(16) ushort sA[128 * 64];
  __shared__ __align__(16) ushort sB[128 * 64];
  const int t = threadIdx.x;
  const int lane = t & 63, w = t >> 6;
  const int g = lane >> 4, lr = lane & 15;
  const int wr = w >> 1, wc = w & 1;

  const int id = blockIdx.x;
  const int xcd = id & 7, wi = id >> 3;
  const int bn = (xcd & 1) * 12 + wi % 12;
  const int bm = (xcd >> 1) * 8 + wi / 12;

  int srow[4], soff[4];
#pragma unroll
  for (int i = 0; i < 4; ++i) {
    const int c = 4 * w + i;
    const int r = c * 8 + (lane >> 3);
    const int sl = (lane & 7) ^ (((r & 3) << 1) ^ ((r >> 3) & 3));
    srow[i] = r;
    soff[i] = sl * 8;
  }

  int raswz[4], rbswz[4];
#pragma unroll
  for (int rs = 0; rs < 4; ++rs) {
    const int ra = wr * 64 + rs * 16 + lr;
    raswz[rs] = ((((ra & 3) << 1) ^ ((ra >> 3) & 3)) << 4);
    const int rb = wc * 64 + rs * 16 + lr;
    rbswz[rs] = ((((rb & 3) << 1) ^ ((rb >> 3) & 3)) << 4);
  }

  f32x4 acc[4][4] = {};

  for (int kt = 0; kt < 1024; kt += 64) {
#pragma unroll
    for (int i = 0; i < 4; ++i) {
      gl16(xh + (size_t)(bm * 128 + srow[i]) * 1024 + kt + soff[i],
           sA + (4 * w + i) * 512);
      gl16(wt + (size_t)(bn * 128 + srow[i]) * 1024 + kt + soff[i],
           sB + (4 * w + i) * 512);
    }
    __syncthreads();
#pragma unroll
    for (int ks = 0; ks < 64; ks += 32) {
      half8 af[4], bb[4];
#pragma unroll
      for (int rs = 0; rs < 4; ++rs) {
        const int ra = wr * 64 + rs * 16 + lr;
        af[rs] = *reinterpret_cast<const half8*>(
            (const char*)sA + ra * 128 + ((16 * g + 2 * ks) ^ raswz[rs]));
      }
#pragma unroll
      for (int cs = 0; cs < 4; ++cs) {
        const int rb = wc * 64 + cs * 16 + lr;
        bb[cs] = *reinterpret_cast<const half8*>(
            (const char*)sB + rb * 128 + ((16 * g + 2 * ks) ^ rbswz[cs]));
      }
#pragma unroll
      for (int rs = 0; rs < 4; ++rs)
#pragma unroll
        for (int cs = 0; cs < 4; ++cs)
          acc[rs][cs] = MFMA16(af[rs], bb[cs], acc[rs][cs]);
    }
    __syncthreads();
  }

  const int m0 = bm * 128 + wr * 64;
  const int n0 = bn * 128 + wc * 64;
  const int which = n0 >> 10;
  const int h = (n0 >> 6) & 15;

  if (which == 2) {
    ushort* q = (w < 2) ? sA + w * 4096 : sB + (w - 2) * 4096;
#pragma unroll
    for (int rs = 0; rs < 4; ++rs)
#pragma unroll
      for (int r = 0; r < 4; ++r) {
        const int m = rs * 16 + g * 4 + r;
#pragma unroll
        for (int cs = 0; cs < 4; ++cs) {
          const int n = cs * 16 + lr;
          q[n * 64 + ((((m >> 3) ^ (n & 7)) << 3) | (m & 7))] =
              hfbits(acc[rs][cs][r]);
        }
      }
    const int vb = m0 >> 11, vs = m0 & 2047;
    ushort* vbase = vt + ((size_t)((vb << 4) + h) * 64) * 2048 + vs;
#pragma unroll
    for (int j = 0; j < 8; ++j) {
      const int dl = j * 8 + (lane >> 3);
      const int mc = lane & 7;
      uint4 vv = *reinterpret_cast<const uint4*>(
          q + dl * 64 + ((mc ^ (dl & 7)) << 3));
      *reinterpret_cast<uint4*>(vbase + (size_t)dl * 2048 + mc * 8) = vv;
    }
  } else {
    ushort* dst = which == 0 ? qw : kw;
    const float qsc = which == 0 ? 1.44269504088896f : 1.0f;  // log2(e) for Q
#pragma unroll
    for (int rs = 0; rs < 4; ++rs) {
#pragma unroll
      for (int r = 0; r < 4; ++r) {
        int m = m0 + rs * 16 + g * 4 + r;
        int b = m >> 11, s = m & 2047;
        ushort* rowp = dst + ((size_t)((b << 4) + h) * 2048 + s) * 64;
#pragma unroll
        for (int cs = 0; cs < 4; ++cs)
          rowp[cs * 16 + lr] = hfbits(acc[rs][cs][r] * qsc);
      }
    }
  }
}

// ---------------------------------------------------------------------------
// Kernel 3: flash attention, 32 q-rows/wave + IN-BLOCK KV-split.
// R9 lesson: the 32q/wave inner loop is right (conflicts halved, k_attn
// 65->56) but the global partial merge (k_comb + 48MB round trip) ate the
// gain.  Now waves 0-3 stream KV[0:1024] and waves 4-7 stream KV[1024:2048]
// for the SAME 128 q-rows; after the main loop half-1 waves dump (m,den,o)
// into the dead K/V LDS, one barrier, half-0 waves apply the exact
// online-softmax combine and write the final normalized output.  No 4th
// kernel, no partial HBM traffic.  LDS 64KB -> 2 blocks/CU = 16 waves/CU.
// ---------------------------------------------------------------------------
__global__ __launch_bounds__(512, 4) void k_attn(const ushort* __restrict__ qw,
                                                 const ushort* __restrict__ kw,
                                                 const ushort* __restrict__ vt,
                                                 const float* __restrict__ biasf,
                                                 float* __restrict__ out) {
  __shared__ __align__(16) ushort sK[2][2][64][64];   // [kvhalf][buf] 32 KB
  __shared__ __align__(16) ushort sV[2][2][64][64];   // [kvhalf][buf] 32 KB

  const int t = threadIdx.x;
  const int lane = t & 63, w = t >> 6;             // w in 0..7
  const int g = lane >> 4, lr = lane & 15;
  const int h2 = w >> 2, wq = w & 3;               // KV half, wave-in-half

  // XCD-clustered decode: id%8 = XCD; 4 bh x 16 qblk per XCD.
  const int id = blockIdx.x;                        // 0..511
  const int j = id >> 3;
  const int bh = (id & 7) * 4 + (j >> 4);
  const int qblk = j & 15;
  const int b = bh >> 4, h = bh & 15;
  const int jt0 = h2 * 1024;

  // Q for both 16-row groups (B-operand; B col = lane&15 = q-row in group)
  const int qrowA = qblk * 128 + wq * 32 + lr;
  const ushort* qpA = qw + ((size_t)bh * 2048 + qrowA) * 64;
  const half8 qA0 = *reinterpret_cast<const half8*>(qpA + g * 8);
  const half8 qA1 = *reinterpret_cast<const half8*>(qpA + 32 + g * 8);
  const ushort* qpB = qpA + 16 * 64;
  const half8 qB0 = *reinterpret_cast<const half8*>(qpB + g * 8);
  const half8 qB1 = *reinterpret_cast<const half8*>(qpB + 32 + g * 8);

  const ushort* kbh = kw + (size_t)bh * 2048 * 64;
  const ushort* vbh = vt + (size_t)bh * 64 * 2048;
  const float* biasb = biasf + b * 2048;

  const int krbase = (lr >> 2) * 8 + (lr & 3);
  const int kswz = (((lr & 3) << 1) ^ (lr >> 2)) << 4;

  // staging: wave wq stages chunks {2wq, 2wq+1} (rows 16wq..16wq+15) of its
  // half's K and V tiles; source column XOR-swizzled (involution).
  const int sr0 = wq * 16 + (lane >> 3);
  const int sr1 = sr0 + 8;
  const int scb = (lane & 7) << 4;
  const int swz0 = scb ^ ((((sr0 & 3) << 1) ^ ((sr0 >> 3) & 3)) << 4);
  const int swz1 = scb ^ ((((sr1 & 3) << 1) ^ ((sr1 >> 3) & 3)) << 4);

  auto stage = [&](int bufi, int jtn) {
    gl16(kbh + (size_t)(jtn + sr0) * 64 + (swz0 >> 1),
         &sK[h2][bufi][0][0] + (wq * 2 + 0) * 512);
    gl16(kbh + (size_t)(jtn + sr1) * 64 + (swz1 >> 1),
         &sK[h2][bufi][0][0] + (wq * 2 + 1) * 512);
    gl16(vbh + (size_t)sr0 * 2048 + jtn + (swz0 >> 1),
         &sV[h2][bufi][0][0] + (wq * 2 + 0) * 512);
    gl16(vbh + (size_t)sr1 * 2048 + jtn + (swz1 >> 1),
         &sV[h2][bufi][0][0] + (wq * 2 + 1) * 512);
  };

  const half8 vones = {(_Float16)1.f, (_Float16)1.f, (_Float16)1.f, (_Float16)1.f,
                       (_Float16)1.f, (_Float16)1.f, (_Float16)1.f, (_Float16)1.f};

  float mA = -__builtin_inff(), mB = -__builtin_inff();
  f32x4 oA[4] = {}, oB[4] = {};
  f32x4 odenA = {}, odenB = {};

  auto sm_step = [&](float (&st)[4][4], float& m_run, f32x4 (&o)[4],
                     f32x4& oden, unsigned int (&pd)[8]) {
    float ma = fmaxf(fmaxf(st[0][0], st[0][1]), st[0][2]);
    ma = fmaxf(fmaxf(ma, st[0][3]), st[1][0]);
    ma = fmaxf(fmaxf(ma, st[1][1]), st[1][2]);
    ma = fmaxf(ma, st[1][3]);
    float mb2 = fmaxf(fmaxf(st[2][0], st[2][1]), st[2][2]);
    mb2 = fmaxf(fmaxf(mb2, st[2][3]), st[3][0]);
    mb2 = fmaxf(fmaxf(mb2, st[3][1]), st[3][2]);
    mb2 = fmaxf(mb2, st[3][3]);
    float tmax = fmaxf(ma, mb2);
    tmax = fmaxf(tmax, __shfl_xor(tmax, 16));
    tmax = fmaxf(tmax, __shfl_xor(tmax, 32));

    if (!__all(tmax <= m_run + 8.f)) {
      const float mnew = fmaxf(m_run, tmax);
      const float sc = __builtin_amdgcn_exp2f(m_run - mnew);  // exp2(-inf)=0
      const float s0 = __shfl(sc, g * 4 + 0);
      const float s1 = __shfl(sc, g * 4 + 1);
      const float s2 = __shfl(sc, g * 4 + 2);
      const float s3 = __shfl(sc, g * 4 + 3);
#pragma unroll
      for (int dn = 0; dn < 4; ++dn) {
        o[dn][0] *= s0; o[dn][1] *= s1; o[dn][2] *= s2; o[dn][3] *= s3;
      }
      oden[0] *= s0; oden[1] *= s1; oden[2] *= s2; oden[3] *= s3;
      m_run = mnew;
    }

#pragma unroll
    for (int jn = 0; jn < 4; ++jn) {
      float p0 = __builtin_amdgcn_exp2f(st[jn][0] - m_run);
      float p1 = __builtin_amdgcn_exp2f(st[jn][1] - m_run);
      float p2 = __builtin_amdgcn_exp2f(st[jn][2] - m_run);
      float p3 = __builtin_amdgcn_exp2f(st[jn][3] - m_run);
      pd[jn * 2 + 0] = __builtin_bit_cast(unsigned int, __builtin_amdgcn_cvt_pkrtz(p0, p1));
      pd[jn * 2 + 1] = __builtin_bit_cast(unsigned int, __builtin_amdgcn_cvt_pkrtz(p2, p3));
    }
  };

  stage(0, jt0);
  __syncthreads();
  int buf = 0;

  for (int it = 0; it < 16; ++it) {
    const int jt = jt0 + it * 64;
    if (it + 1 < 16) stage(buf ^ 1, jt + 64);

    // ---- QK for BOTH groups (K fragments read once)
    float stA[4][4], stB[4][4];
#pragma unroll
    for (int jn = 0; jn < 4; ++jn) {
      const int koff = (jn & 1) * 4 + (jn >> 1) * 32;
      const f32x4 bias4 = *reinterpret_cast<const f32x4*>(biasb + jt + koff + g * 8);
      const int kr = koff + krbase;
      const char* krow = (const char*)&sK[h2][buf][kr][0];
      half8 ka0 = *reinterpret_cast<const half8*>(krow + ((16 * g) ^ kswz));
      half8 ka1 = *reinterpret_cast<const half8*>(krow + ((64 + 16 * g) ^ kswz));
      f32x4 s4A = bias4;
      s4A = MFMA16(ka0, qA0, s4A);
      s4A = MFMA16(ka1, qA1, s4A);
      f32x4 s4B = bias4;
      s4B = MFMA16(ka0, qB0, s4B);
      s4B = MFMA16(ka1, qB1, s4B);
#pragma unroll
      for (int r = 0; r < 4; ++r) { stA[jn][r] = s4A[r]; stB[jn][r] = s4B[r]; }
    }

    // ---- softmax both groups (VALU; overlaps other waves' MFMA)
    unsigned int pdA[8], pdB[8];
    sm_step(stA, mA, oA, odenA, pdA);
    sm_step(stB, mB, oB, odenB, pdB);

    // ---- V fragments read once, PV for both groups
    half8 vf0[4], vf1[4];
#pragma unroll
    for (int dn = 0; dn < 4; ++dn) {
      const int vr = dn * 16 + lr;
      const int vswz = ((((lr & 3) << 1) ^ ((2 * dn + (lr >> 3)) & 3)) << 4);
      const char* vrow = (const char*)&sV[h2][buf][vr][0];
      vf0[dn] = *reinterpret_cast<const half8*>(vrow + ((16 * g) ^ vswz));
      vf1[dn] = *reinterpret_cast<const half8*>(vrow + ((64 + 16 * g) ^ vswz));
    }
    union { unsigned int u[4]; half8 hh; } a0, a1, b0, b1;
    a0.u[0] = pdA[0]; a0.u[1] = pdA[1]; a0.u[2] = pdA[2]; a0.u[3] = pdA[3];
    a1.u[0] = pdA[4]; a1.u[1] = pdA[5]; a1.u[2] = pdA[6]; a1.u[3] = pdA[7];
    b0.u[0] = pdB[0]; b0.u[1] = pdB[1]; b0.u[2] = pdB[2]; b0.u[3] = pdB[3];
    b1.u[0] = pdB[4]; b1.u[1] = pdB[5]; b1.u[2] = pdB[6]; b1.u[3] = pdB[7];

    __builtin_amdgcn_s_setprio(1);
#pragma unroll
    for (int dn = 0; dn < 4; ++dn) {
      oA[dn] = MFMA16(a0.hh, vf0[dn], oA[dn]);
      oA[dn] = MFMA16(a1.hh, vf1[dn], oA[dn]);
      oB[dn] = MFMA16(b0.hh, vf0[dn], oB[dn]);
      oB[dn] = MFMA16(b1.hh, vf1[dn], oB[dn]);
    }
    odenA = MFMA16(a0.hh, vones, odenA);
    odenA = MFMA16(a1.hh, vones, odenA);
    odenB = MFMA16(b0.hh, vones, odenB);
    odenB = MFMA16(b1.hh, vones, odenB);
    __builtin_amdgcn_s_setprio(0);

    __syncthreads();
    buf ^= 1;
  }

  // ---- in-block merge of the two KV halves (exact online-softmax combine).
  // K/V LDS is dead now; overlay partial-state arrays on it.
  float* oL  = (float*)&sK[0][0][0][0];   // [(wq*2+grp)][16 q][64 d] = 32 KB
  float* mL0 = (float*)&sV[0][0][0][0];   // [(wq*2+grp)*16 + q] half-0 m
  float* mL1 = mL0 + 128;                 // half-1 m
  float* dL1 = mL0 + 256;                 // half-1 den

  if (h2 == 0) {
    if (g == 0) {
      mL0[(wq * 2 + 0) * 16 + lr] = mA;
      mL0[(wq * 2 + 1) * 16 + lr] = mB;
    }
  } else {
    if (g == 0) {
      mL1[(wq * 2 + 0) * 16 + lr] = mA;
      mL1[(wq * 2 + 1) * 16 + lr] = mB;
    }
    if (lr == 0) {
#pragma unroll
      for (int r = 0; r < 4; ++r) {
        dL1[(wq * 2 + 0) * 16 + g * 4 + r] = odenA[r];
        dL1[(wq * 2 + 1) * 16 + g * 4 + r] = odenB[r];
      }
    }
#pragma unroll
    for (int dn = 0; dn < 4; ++dn)
#pragma unroll
      for (int r = 0; r < 4; ++r) {
        oL[((wq * 2 + 0) * 16 + g * 4 + r) * 64 + dn * 16 + lr] = oA[dn][r];
        oL[((wq * 2 + 1) * 16 + g * 4 + r) * 64 + dn * 16 + lr] = oB[dn][r];
      }
  }
  __syncthreads();

  if (h2 == 0) {
    auto merge_out = [&](f32x4 (&o)[4], f32x4& oden, int grp) {
      const int si = (wq * 2 + grp) * 16;
      float c0[4], c1[4];
#pragma unroll
      for (int r = 0; r < 4; ++r) {
        const int q = g * 4 + r;
        const float m0 = mL0[si + q], m1 = mL1[si + q];
        const float mm = fmaxf(m0, m1);
        const float w0 = __builtin_amdgcn_exp2f(m0 - mm);
        const float w1 = __builtin_amdgcn_exp2f(m1 - mm);
        const float rd = 1.f / (w0 * oden[r] + w1 * dL1[si + q]);
        c0[r] = w0 * rd;
        c1[r] = w1 * rd;
      }
      const int s0r = qblk * 128 + wq * 32 + grp * 16 + g * 4;
      float* ob = out + ((size_t)b * 2048 + s0r) * 1024 + h * 64;
#pragma unroll
      for (int dn = 0; dn < 4; ++dn)
#pragma unroll
        for (int r = 0; r < 4; ++r) {
          const float o1 = oL[(si + g * 4 + r) * 64 + dn * 16 + lr];
          ob[(size_t)r * 1024 + dn * 16 + lr] = o[dn][r] * c0[r] + o1 * c1[r];
        }
    };
    merge_out(oA, odenA, 0);
    merge_out(oB, odenB, 1);
  }
}

// ---------------------------------------------------------------------------
extern "C" void kernel_launch(void* const* d_in, const int* in_sizes, int n_in,
                              void* d_out, int out_size, void* d_ws, size_t ws_size,
                              hipStream_t stream) {
  const float* x = (const float*)d_in[0];     // [2][2048][1024] f32
  const float* W = (const float*)d_in[1];     // [1024][3072] f32
  const int* mask = (const int*)d_in[2];      // [2][2048] i32
  float* out = (float*)d_out;                 // [2][2048][1024] f32
  char* ws = (char*)d_ws;

  ushort* wt = (ushort*)(ws);                                  // 6,291,456 B
  ushort* qw = (ushort*)(ws + 6291456);                        // 8,388,608 B
  ushort* kw = (ushort*)(ws + 6291456 + 8388608);              // 8,388,608 B
  ushort* xh = (ushort*)(ws + 6291456 + 2 * (size_t)8388608);  // 8,388,608 B
  ushort* vt = (ushort*)(ws + 6291456 + 3 * (size_t)8388608);  // 8,388,608 B
  float* biasf = (float*)(ws + 6291456 + 4 * (size_t)8388608); // 16,384 B

  k_prep<<<dim3(2816), 256, 0, stream>>>(W, wt, x, xh, mask, biasf);
  k_gemm<<<dim3(768), 256, 0, stream>>>(xh, wt, qw, kw, vt);
  k_attn<<<dim3(512), 512, 0, stream>>>(qw, kw, vt, biasf, out);
}